// Round 8
// baseline (672.864 us; speedup 1.0000x reference)
//
#include <hip/hip_runtime.h>

// OptionNet on MI355X — split-bf16 MFMA path, async-staged (global_load_lds),
// R7: counted-vmcnt no-drain K-loop barriers (T3/T4) + setprio (T5).
//
//   k_split_obs:  obs f32 -> 2 bf16 planes [2][32768][512] (ws)
//   k_split_hid:  10 hidden W -> 2 bf16 planes, [n][k] layout (ws)
//   k_split_head: 10 head sets -> 2 bf16 planes, [32 cols][k] padded (ws)
//   k_gemm<3>:    fused meta+term GEMMs (128x128 tile, 4 waves, K-step 32,
//                 3-term MFMA split: hi*hi + hi*lo + lo*hi).
//   k_epi_mt:     meta argmax/softmax/value + termination sigmoid + bucketing.
//   k_gemm<2>:    per-option sub-policy on bucketed rows only (1/8 FLOPs).
//   k_epi_sub:    sub argmax/softmax/value.
//   K-loop schedule (APL path): per step
//     stage(next tile: 8 global_load_lds) ; s_waitcnt vmcnt(8) ; s_barrier ;
//     setprio(1) ; 48 MFMA ; setprio(0) ; s_barrier
//   -> prefetch loads stay in flight across barriers (never drain to 0 in loop).
//   Fallbacks: mid-ws (A reg-staged, plain __syncthreads) and fp32 (Round-2).

constexpr int Bn = 32768;
constexpr int Dk = 512;
constexpr int Hn = 1024;

typedef __attribute__((ext_vector_type(8))) short short8v;
typedef __attribute__((ext_vector_type(4))) float f32x4;

__device__ __forceinline__ unsigned short f2bf(float x) {
    unsigned u = __float_as_uint(x);
    u += 0x7FFFu + ((u >> 16) & 1u);
    return (unsigned short)(u >> 16);
}
__device__ __forceinline__ float bf2f(unsigned short h) {
    return __uint_as_float(((unsigned)h) << 16);
}

__device__ __forceinline__ void gload16(const void* g, void* l) {
    __builtin_amdgcn_global_load_lds(
        (const __attribute__((address_space(1))) unsigned int*)g,
        (__attribute__((address_space(3))) unsigned int*)l, 16, 0, 0);
}

// ---------------- workspace layout ----------------
constexpr size_t WS_COUNTS  = 0;           // 8 ints
constexpr size_t WS_DFLAG   = 32;          // 1 int
constexpr size_t WS_BUCKETS = 64;          // u16 [8][32768]
constexpr size_t WS_LOGITS  = 1u << 20;    // 3 x [32768][20] f32
constexpr size_t LOG_SZ     = (size_t)Bn * 20 * 4;
constexpr size_t WS_HID     = 16u << 20;   // [10][2][1024][512] bf16
constexpr size_t WS_HEAD    = 40u << 20;   // [10][2][32][1024] bf16
constexpr size_t WS_OBS     = 42u << 20;   // [2][32768][512] bf16
constexpr size_t MID_NEED   = WS_HEAD + (size_t)10 * 2 * 32 * 1024 * 2;
constexpr size_t FULL_NEED  = WS_OBS + (size_t)2 * Bn * Dk * 2;

// ---------------- dones layout detect ----------------
__global__ void k_detect(const unsigned int* __restrict__ w, int* __restrict__ flag)
{
    unsigned int acc = 0;
    for (int i = threadIdx.x; i < 8192; i += blockDim.x) acc |= w[i];
    if (acc & 0xFFFFFF00u) atomicOr(flag, 1);
}

// ---------------- prep kernels ----------------
__global__ __launch_bounds__(256)
void k_split_obs(const float* __restrict__ obs, unsigned short* __restrict__ dst)
{
    const size_t i = ((size_t)blockIdx.x * 256 + threadIdx.x) * 8;
    const float4 v0 = *(const float4*)(obs + i);
    const float4 v1 = *(const float4*)(obs + i + 4);
    const float xs[8] = {v0.x, v0.y, v0.z, v0.w, v1.x, v1.y, v1.z, v1.w};
    short8v hi, lo;
#pragma unroll
    for (int e = 0; e < 8; ++e) {
        const unsigned short h = f2bf(xs[e]);
        hi[e] = (short)h;
        lo[e] = (short)f2bf(xs[e] - bf2f(h));
    }
    *(short8v*)(dst + i) = hi;
    *(short8v*)(dst + (size_t)Bn * Dk + i) = lo;
}

__global__ __launch_bounds__(256)
void k_split_hid(const float* __restrict__ Wm1, const float* __restrict__ Wt1,
                 const float* __restrict__ W1, unsigned short* __restrict__ dst)
{
    const int bid = blockIdx.x;
    const int m  = bid >> 7;
    const int t  = bid & 127;
    const int k0 = (t >> 4) << 6;
    const int n0 = (t & 15) << 6;
    const float* src = (m == 0) ? Wm1 : (m == 1) ? Wt1 : (W1 + (size_t)(m - 2) * Dk * Hn);

    __shared__ unsigned short sT[2][64][72];
    const int tid = threadIdx.x;
    const int kk = tid >> 2;
    const int nc = (tid & 3) << 4;
    const float* p = src + (size_t)(k0 + kk) * Hn + n0 + nc;
#pragma unroll
    for (int i = 0; i < 4; ++i) {
        const float4 v = *(const float4*)(p + i * 4);
        float xs[4] = {v.x, v.y, v.z, v.w};
#pragma unroll
        for (int e = 0; e < 4; ++e) {
            const unsigned short h = f2bf(xs[e]);
            const unsigned short l = f2bf(xs[e] - bf2f(h));
            sT[0][nc + i * 4 + e][kk] = h;
            sT[1][nc + i * 4 + e][kk] = l;
        }
    }
    __syncthreads();
    if (tid < 128) {
        const int pl = tid >> 6, n = tid & 63;
        unsigned short* dp = dst + ((size_t)(m * 2 + pl) * 1024 + n0 + n) * 512 + k0;
        const unsigned short* sp = &sT[pl][n][0];
#pragma unroll
        for (int i = 0; i < 8; ++i)
            *(short8v*)(dp + i * 8) = *(const short8v*)(sp + i * 8);
    }
}

__global__ __launch_bounds__(256)
void k_split_head(const float* __restrict__ Wm_pi, const float* __restrict__ Wm_v,
                  const float* __restrict__ Wt2, const float* __restrict__ Wpi,
                  const float* __restrict__ Wv, unsigned short* __restrict__ dst)
{
    const int set = blockIdx.x >> 5, c = blockIdx.x & 31;
    const int tid = threadIdx.x;
    unsigned short* d0 = dst + ((size_t)(set * 2 + 0) * 32 + c) * 1024;
    unsigned short* d1 = dst + ((size_t)(set * 2 + 1) * 32 + c) * 1024;
#pragma unroll
    for (int i = 0; i < 4; ++i) {
        const int k = tid + i * 256;
        float x = 0.f;
        if (set == 0)      { if (c < 8) x = Wm_pi[k * 8 + c]; else if (c == 8) x = Wm_v[k]; }
        else if (set == 1) { if (c < 8) x = Wt2[k * 8 + c]; }
        else { const int o = set - 2;
               if (c < 16) x = Wpi[((size_t)o * 1024 + k) * 16 + c];
               else if (c == 16) x = Wv[o * 1024 + k]; }
        const unsigned short h = f2bf(x);
        d0[k] = h;
        d1[k] = f2bf(x - bf2f(h));
    }
}

// ---------------- main fused GEMM ----------------
// LDS s_raw map (bytes):
//   K-loop:  A planes [buf][pl][128 rows][64B]  at 0      .. 32767
//            B planes [buf][pl][128 cols][64B]  at 32768  .. 65535
//   post-K:  s_h  f32 [64][132]                 at 0      .. 33791
//            s_hB bf16 [pl][32 cols][272B]      at 33792  .. 51199
// MODE 3: fused meta+term (bid = x(3) | ch(3) | mat(1) | rtHigh)
// MODE 2: sub-policy on bucketed rows (bid = o(3 hi) | rt/ch interleave)
template<int MODE, bool APL>
__global__ __launch_bounds__(256, 2)
void k_gemm(const float* __restrict__ obs,
            const unsigned short* __restrict__ obsPl,
            const unsigned short* __restrict__ hidPl,
            const unsigned short* __restrict__ headPl,
            const float* __restrict__ bm1,
            const float* __restrict__ b1,
            float* __restrict__ metaL, float* __restrict__ termL,
            float* __restrict__ subL,
            const int* __restrict__ counts,
            const unsigned short* __restrict__ buckets)
{
    __shared__ __align__(16) unsigned char s_raw[65536];
    __shared__ float s_bias[128];
    __shared__ int   s_idx[128];

    const int tid = threadIdx.x;
    const int bid = blockIdx.x;

    int mat, set, ch, CT, nrows = 128;
    float* L;
    const float* bias = nullptr;

    if constexpr (MODE == 2) {
        const int o = bid >> 11, rem = bid & 2047;
        const int x = rem & 7;  ch = (rem >> 3) & 7;
        const int rt = x + ((rem >> 6) << 3);
        const int n = counts[o], start = rt << 7;
        if (start >= n) return;                  // uniform early exit, pre-sync
        nrows = min(128, n - start);
        if (tid < 128) s_idx[tid] = (int)buckets[(o << 15) + start + min(tid, nrows - 1)];
        mat = 2 + o; set = 2 + o; bias = b1 + (size_t)o * Hn; L = subL; CT = 17;
    } else {                                     // MODE 3: fused meta + term
        const int x = bid & 7;  ch = (bid >> 3) & 7;  mat = (bid >> 6) & 1;
        const int rt = x + ((bid >> 7) << 3);
        if (tid < 128) s_idx[tid] = (rt << 7) + tid;
        set = mat; CT = mat ? 8 : 9;
        L = mat ? termL : metaL;
        bias = mat ? nullptr : bm1;
    }
    const int hc = ch << 7;
    if (tid < 128) s_bias[tid] = (bias == nullptr) ? 0.f : bias[hc + tid];
    __syncthreads();

    const int l = tid & 63, w = tid >> 6;
    const int r15 = l & 15, qq = l >> 4;
    const int R0 = (w >> 1) * 64, C0 = (w & 1) * 64;

    f32x4 acc[4][4];
#pragma unroll
    for (int i = 0; i < 4; ++i)
#pragma unroll
        for (int j = 0; j < 4; ++j) acc[i][j] = (f32x4){0.f, 0.f, 0.f, 0.f};

    // ---- staging bases (per-lane global addresses, pre-XOR'd quads) ----
    const int spl = w >> 1;                 // plane this wave stages
    const int sg0 = (w & 1) * 4;            // first 16-row/col group
    const unsigned char* bB[4];
#pragma unroll
    for (int j = 0; j < 4; ++j) {
        const int cl = (sg0 + j) * 16 + (l >> 2);
        const int qd = ((l & 3) ^ ((cl >> 1) & 3)) << 4;
        bB[j] = (const unsigned char*)hidPl
              + ((size_t)(mat * 2 + spl) * 1024 + hc + cl) * 1024 + qd;
    }
    const unsigned char* aB[4];
    if constexpr (APL) {
#pragma unroll
        for (int j = 0; j < 4; ++j) {
            const int rl = (sg0 + j) * 16 + (l >> 2);
            const int qd = ((l & 3) ^ ((rl >> 1) & 3)) << 4;
            aB[j] = (const unsigned char*)obsPl
                  + ((size_t)spl * Bn + (size_t)s_idx[rl]) * 1024 + qd;
        }
    }

    auto stage = [&](int buf, int kt) {
#pragma unroll
        for (int j = 0; j < 4; ++j) {
            if constexpr (APL)
                gload16(aB[j] + kt * 64,
                        s_raw + (buf * 2 + spl) * 8192 + (sg0 + j) * 1024);
            gload16(bB[j] + kt * 64,
                    s_raw + 32768 + (buf * 2 + spl) * 8192 + (sg0 + j) * 1024);
        }
    };

    // ---- A reg-staging fallback (mid-ws path) ----
    const int arow = tid >> 1, ahalf = tid & 1;
    size_t arowg = 0;
    if constexpr (!APL) arowg = (size_t)s_idx[arow] * Dk;
    float4 av[4];
    auto loadA = [&](int kt) {
        const float* p = obs + arowg + kt * 32 + ahalf * 16;
        av[0] = *(const float4*)(p);      av[1] = *(const float4*)(p + 4);
        av[2] = *(const float4*)(p + 8);  av[3] = *(const float4*)(p + 12);
    };
    auto writeA = [&](int buf) {
        float xs[16] = {av[0].x, av[0].y, av[0].z, av[0].w,  av[1].x, av[1].y, av[1].z, av[1].w,
                        av[2].x, av[2].y, av[2].z, av[2].w,  av[3].x, av[3].y, av[3].z, av[3].w};
        short8v H0, H1, Lo0, Lo1;
#pragma unroll
        for (int e = 0; e < 8; ++e) {
            unsigned short h = f2bf(xs[e]);
            H0[e] = (short)h;  Lo0[e] = (short)f2bf(xs[e] - bf2f(h));
            h = f2bf(xs[8 + e]);
            H1[e] = (short)h;  Lo1[e] = (short)f2bf(xs[8 + e] - bf2f(h));
        }
        const int sw = (arow >> 1) & 3;
        const int ra = arow * 64;
        unsigned char* a0 = s_raw + (buf * 2 + 0) * 8192 + ra;
        unsigned char* a1 = s_raw + (buf * 2 + 1) * 8192 + ra;
        const int q0 = ((2 * ahalf) ^ sw) << 4, q1 = ((2 * ahalf + 1) ^ sw) << 4;
        *(short8v*)(a0 + q0) = H0;  *(short8v*)(a0 + q1) = H1;
        *(short8v*)(a1 + q0) = Lo0; *(short8v*)(a1 + q1) = Lo1;
    };

    auto mfma_step = [&](int buf) {
        short8v a[2][4], b[2][4];
#pragma unroll
        for (int rf = 0; rf < 4; ++rf) {
            const int row = R0 + rf * 16 + r15;
            const int off = row * 64 + ((qq ^ ((row >> 1) & 3)) << 4);
            a[0][rf] = *(const short8v*)(s_raw + (buf * 2 + 0) * 8192 + off);
            a[1][rf] = *(const short8v*)(s_raw + (buf * 2 + 1) * 8192 + off);
        }
#pragma unroll
        for (int cf = 0; cf < 4; ++cf) {
            const int n = C0 + cf * 16 + r15;
            const int off = n * 64 + ((qq ^ ((n >> 1) & 3)) << 4);
            b[0][cf] = *(const short8v*)(s_raw + 32768 + (buf * 2 + 0) * 8192 + off);
            b[1][cf] = *(const short8v*)(s_raw + 32768 + (buf * 2 + 1) * 8192 + off);
        }
        // 3-term split: lo*hi + hi*lo + hi*hi (lo*lo dropped, ~2^-18 relative)
#pragma unroll
        for (int rf = 0; rf < 4; ++rf)
#pragma unroll
            for (int cf = 0; cf < 4; ++cf)
                acc[rf][cf] = __builtin_amdgcn_mfma_f32_16x16x32_bf16(
                    a[1][rf], b[0][cf], acc[rf][cf], 0, 0, 0);
#pragma unroll
        for (int rf = 0; rf < 4; ++rf)
#pragma unroll
            for (int cf = 0; cf < 4; ++cf)
                acc[rf][cf] = __builtin_amdgcn_mfma_f32_16x16x32_bf16(
                    a[0][rf], b[1][cf], acc[rf][cf], 0, 0, 0);
#pragma unroll
        for (int rf = 0; rf < 4; ++rf)
#pragma unroll
            for (int cf = 0; cf < 4; ++cf)
                acc[rf][cf] = __builtin_amdgcn_mfma_f32_16x16x32_bf16(
                    a[0][rf], b[0][cf], acc[rf][cf], 0, 0, 0);
    };

    if constexpr (APL) {
        // ---- T3/T4 schedule: counted vmcnt, loads in flight across barriers.
        // Per wave: each stage() issues exactly 8 global_load_lds (4 A + 4 B).
        // vmcnt(8) => the PREVIOUS tile's 8 loads have landed; the 8 just
        // issued stay in flight under the MFMA phase. Never drain in-loop.
        stage(0, 0);
        asm volatile("s_waitcnt vmcnt(0)" ::: "memory");
        __builtin_amdgcn_s_barrier();
#pragma unroll 2
        for (int kt = 0; kt < 16; ++kt) {
            const int cb = kt & 1;
            if (kt < 15) {
                stage(cb ^ 1, kt + 1);
                asm volatile("s_waitcnt vmcnt(8)" ::: "memory");
            } else {
                asm volatile("s_waitcnt vmcnt(0)" ::: "memory");  // pre-head drain
            }
            __builtin_amdgcn_s_barrier();           // all waves' tile-cb loads landed
            __builtin_amdgcn_sched_barrier(0);      // no ds_read hoist above barrier
            __builtin_amdgcn_s_setprio(1);
            mfma_step(cb);
            __builtin_amdgcn_s_setprio(0);
            __builtin_amdgcn_sched_barrier(0);      // no MFMA/ds_read sink below
            __builtin_amdgcn_s_barrier();           // reads of cb done before overwrite
        }
    } else {
        loadA(0);
        stage(0, 0);          // B only (A skipped by constexpr)
        writeA(0);
        __syncthreads();
#pragma unroll 2
        for (int kt = 0; kt < 16; ++kt) {
            const int cb = kt & 1;
            if (kt < 15) { loadA(kt + 1); stage(cb ^ 1, kt + 1); }
            mfma_step(cb);
            if (kt < 15) writeA(cb ^ 1);
            __syncthreads();
        }
    }

    // ---- stage head-weight planes into s_hB ----
    {
        const int pl = tid >> 7, idx = tid & 127, c = idx >> 2, kq = idx & 3;
        const unsigned short* hp = headPl + ((size_t)(set * 2 + pl) * 32 + c) * 1024 + hc + kq * 32;
        short8v h0 = *(const short8v*)(hp);      short8v h1 = *(const short8v*)(hp + 8);
        short8v h2 = *(const short8v*)(hp + 16); short8v h3 = *(const short8v*)(hp + 24);
        unsigned char* d = s_raw + 33792 + pl * 8704 + c * 272 + kq * 64;
        ((short8v*)d)[0] = h0; ((short8v*)d)[1] = h1; ((short8v*)d)[2] = h2; ((short8v*)d)[3] = h3;
    }

    float* sh = (float*)s_raw;   // [64][132]
#pragma unroll 1
    for (int half = 0; half < 2; ++half) {
        if ((w >> 1) == half) {           // owning waves write bias+relu(h) rows
#pragma unroll
            for (int rf = 0; rf < 4; ++rf)
#pragma unroll
                for (int cf = 0; cf < 4; ++cf) {
                    const int c = C0 + cf * 16 + r15;
                    const float bs = s_bias[c];
#pragma unroll
                    for (int reg = 0; reg < 4; ++reg) {
                        const int r = rf * 16 + qq * 4 + reg;
                        sh[r * 132 + c] = fmaxf(acc[rf][cf][reg] + bs, 0.f);
                    }
                }
        }
        __syncthreads();

        f32x4 hacc[2];
        hacc[0] = (f32x4){0.f, 0.f, 0.f, 0.f};
        hacc[1] = (f32x4){0.f, 0.f, 0.f, 0.f};
#pragma unroll
        for (int ks = 0; ks < 4; ++ks) {
            const float* shp = sh + (w * 16 + r15) * 132 + ks * 32 + qq * 8;
            const float4 f0 = *(const float4*)(shp);
            const float4 f1 = *(const float4*)(shp + 4);
            const float xs[8] = {f0.x, f0.y, f0.z, f0.w, f1.x, f1.y, f1.z, f1.w};
            short8v ah, al;
#pragma unroll
            for (int j = 0; j < 8; ++j) {
                const unsigned short h = f2bf(xs[j]);
                ah[j] = (short)h;
                al[j] = (short)f2bf(xs[j] - bf2f(h));
            }
#pragma unroll
            for (int cf = 0; cf < 2; ++cf) {
                const unsigned char* hb = s_raw + 33792 + (cf * 16 + r15) * 272 + ks * 64 + qq * 16;
                const short8v b0 = *(const short8v*)(hb);          // hi plane
                const short8v b1v = *(const short8v*)(hb + 8704);  // lo plane
                hacc[cf] = __builtin_amdgcn_mfma_f32_16x16x32_bf16(al, b0, hacc[cf], 0, 0, 0);
                hacc[cf] = __builtin_amdgcn_mfma_f32_16x16x32_bf16(ah, b1v, hacc[cf], 0, 0, 0);
                hacc[cf] = __builtin_amdgcn_mfma_f32_16x16x32_bf16(ah, b0, hacc[cf], 0, 0, 0);
            }
        }
#pragma unroll
        for (int cf = 0; cf < 2; ++cf) {
            const int c = cf * 16 + r15;
            if (c < CT) {
#pragma unroll
                for (int reg = 0; reg < 4; ++reg) {
                    const int rl = half * 64 + w * 16 + qq * 4 + reg;
                    if (rl < nrows)
                        atomicAdd(&L[(size_t)s_idx[rl] * 20 + c], hacc[cf][reg]);
                }
            }
        }
        __syncthreads();
    }
}

// ---------------- epilogues ----------------
__global__ __launch_bounds__(256)
void k_epi_mt(const float* __restrict__ metaL, const float* __restrict__ termL,
              float* __restrict__ out, const int* __restrict__ execopt,
              const void* __restrict__ dones, const int* __restrict__ dflag,
              int* __restrict__ counts, unsigned short* __restrict__ buckets)
{
    const int g = blockIdx.x * 256 + threadIdx.x;
    const float* lr = metaL + (size_t)g * 20;
    float m = lr[0]; int am = 0;
#pragma unroll
    for (int j = 1; j < 8; ++j) { const float x = lr[j]; if (x > m) { m = x; am = j; } }
    float s = 0.f;
#pragma unroll
    for (int j = 0; j < 8; ++j) s += expf(lr[j] - m);
    out[3 * Bn + g] = (float)am;
    out[4 * Bn + g] = lr[8];
    out[5 * Bn + g] = -logf(s);

    const int eo = execopt[g];
    const float logit = termL[(size_t)g * 20 + eo];
    const float p = 1.f / (1.f + expf(-logit));
    out[6 * Bn + g] = p;
    bool dn;
    if (*dflag) dn = ((const unsigned char*)dones)[g] != 0;
    else        dn = ((const int*)dones)[g] != 0;
    const int no = (dn || (p > 0.5f)) ? am : eo;
    const int pos = atomicAdd(&counts[no], 1);
    buckets[(no << 15) + pos] = (unsigned short)g;
}

__global__ __launch_bounds__(256)
void k_epi_sub(const float* __restrict__ L, float* __restrict__ out)
{
    const int g = blockIdx.x * 256 + threadIdx.x;
    const float* lr = L + (size_t)g * 20;
    float m = lr[0]; int am = 0;
#pragma unroll
    for (int j = 1; j < 16; ++j) { const float x = lr[j]; if (x > m) { m = x; am = j; } }
    float s = 0.f;
#pragma unroll
    for (int j = 0; j < 16; ++j) s += expf(lr[j] - m);
    out[0 * Bn + g] = (float)am;
    out[1 * Bn + g] = lr[16];
    out[2 * Bn + g] = -logf(s);
}

// ================= Round-2 fp32 fallback (passing) =================
template<int CA, int CB, bool HASBIAS, int MODE>
__global__ __launch_bounds__(256, 2)
void k_fused_fb(const float* __restrict__ obs, const float* __restrict__ WhB,
                const float* __restrict__ biasB, const float* __restrict__ WAB,
                const float* __restrict__ WBB, float* __restrict__ out,
                int* __restrict__ counts, unsigned short* __restrict__ buckets,
                const void* __restrict__ dones, const int* __restrict__ dflag,
                const int* __restrict__ execopt)
{
    constexpr int CT  = CA + CB;
    constexpr int CPT = (CT + 3) / 4;

    __shared__ float s_obsT[16][68];
    __shared__ float s_W[16][132];
    __shared__ float s_h[64][132];
    __shared__ float s_WhT[17][132];
    __shared__ float s_logits[64][20];
    __shared__ float s_bias[128];
    __shared__ int   s_idx[64];

    const int tid = threadIdx.x;
    int nrows = 64;
    const float* Wh = WhB; const float* bias = biasB;
    const float* WA = WAB; const float* WB = WBB;

    if constexpr (MODE == 2) {
        const int o = blockIdx.x >> 9;
        const int t = blockIdx.x & 511;
        const int n = counts[o];
        const int start = t * 64;
        if (start >= n) return;
        nrows = min(64, n - start);
        if (tid < 64) s_idx[tid] = (int)buckets[o * Bn + start + min(tid, nrows - 1)];
        Wh = WhB + (size_t)o * Dk * Hn; bias = biasB + (size_t)o * Hn;
        WA = WAB + (size_t)o * Hn * 16; WB = WBB + (size_t)o * Hn;
    } else {
        if (tid < 64) s_idx[tid] = blockIdx.x * 64 + tid;
    }
    __syncthreads();

    const int tc = tid & 15, tr = tid >> 4;
    const int hr = tid >> 2, hq = tid & 3;
    const int ld_row = tid >> 2, ld_kk = (tid & 3) * 4;

    float head_acc[CPT];
#pragma unroll
    for (int i = 0; i < CPT; ++i) head_acc[i] = 0.f;

    for (int hcc = 0; hcc < Hn; hcc += 128) {
        for (int e = tid; e < CT * 128; e += 256) {
            const int c = e >> 7, j = e & 127;
            float v;
            if (c < CA) v = WA[(size_t)(hcc + j) * CA + c];
            else        v = WB[(size_t)(hcc + j) * CB + (c - CA)];
            s_WhT[c][j] = v;
        }
        if constexpr (HASBIAS) { if (tid < 128) s_bias[tid] = bias[hcc + tid]; }

        float acc[4][8];
#pragma unroll
        for (int i = 0; i < 4; ++i)
#pragma unroll
            for (int j = 0; j < 8; ++j) acc[i][j] = 0.f;

        for (int kt = 0; kt < Dk; kt += 16) {
            __syncthreads();
            {
                const int gr = s_idx[ld_row];
                const float4 v = *reinterpret_cast<const float4*>(obs + (size_t)gr * Dk + kt + ld_kk);
                s_obsT[ld_kk + 0][ld_row] = v.x; s_obsT[ld_kk + 1][ld_row] = v.y;
                s_obsT[ld_kk + 2][ld_row] = v.z; s_obsT[ld_kk + 3][ld_row] = v.w;
            }
#pragma unroll
            for (int p = 0; p < 2; ++p) {
                const int Li = tid + p * 256;
                const int k = Li >> 5, cg = (Li & 31) * 4;
                *reinterpret_cast<float4*>(&s_W[k][cg]) =
                    *reinterpret_cast<const float4*>(Wh + (size_t)(kt + k) * Hn + hcc + cg);
            }
            __syncthreads();
#pragma unroll
            for (int k = 0; k < 16; ++k) {
                const float4 avv = *reinterpret_cast<const float4*>(&s_obsT[k][tr * 4]);
                const float4 b0 = *reinterpret_cast<const float4*>(&s_W[k][tc * 4]);
                const float4 b1 = *reinterpret_cast<const float4*>(&s_W[k][64 + tc * 4]);
                float a_[4] = {avv.x, avv.y, avv.z, avv.w};
                float b_[8] = {b0.x, b0.y, b0.z, b0.w, b1.x, b1.y, b1.z, b1.w};
#pragma unroll
                for (int i = 0; i < 4; ++i)
#pragma unroll
                    for (int j = 0; j < 8; ++j) acc[i][j] = fmaf(a_[i], b_[j], acc[i][j]);
            }
        }

#pragma unroll
        for (int i = 0; i < 4; ++i) {
            const int r = tr * 4 + i;
            float4 v0, v1;
            v0.x = acc[i][0]; v0.y = acc[i][1]; v0.z = acc[i][2]; v0.w = acc[i][3];
            v1.x = acc[i][4]; v1.y = acc[i][5]; v1.z = acc[i][6]; v1.w = acc[i][7];
            if constexpr (HASBIAS) {
                v0.x += s_bias[tc * 4 + 0]; v0.y += s_bias[tc * 4 + 1];
                v0.z += s_bias[tc * 4 + 2]; v0.w += s_bias[tc * 4 + 3];
                v1.x += s_bias[64 + tc * 4 + 0]; v1.y += s_bias[64 + tc * 4 + 1];
                v1.z += s_bias[64 + tc * 4 + 2]; v1.w += s_bias[64 + tc * 4 + 3];
            }
            v0.x = fmaxf(v0.x, 0.f); v0.y = fmaxf(v0.y, 0.f);
            v0.z = fmaxf(v0.z, 0.f); v0.w = fmaxf(v0.w, 0.f);
            v1.x = fmaxf(v1.x, 0.f); v1.y = fmaxf(v1.y, 0.f);
            v1.z = fmaxf(v1.z, 0.f); v1.w = fmaxf(v1.w, 0.f);
            *reinterpret_cast<float4*>(&s_h[r][tc * 4]) = v0;
            *reinterpret_cast<float4*>(&s_h[r][64 + tc * 4]) = v1;
        }
        __syncthreads();
        {
            const float* hrow = s_h[hr];
#pragma unroll
            for (int i = 0; i < CPT; ++i) {
                const int c = hq * CPT + i;
                if (c < CT) {
                    const float* wrow = s_WhT[c];
                    float a = head_acc[i];
#pragma unroll
                    for (int j = 0; j < 128; j += 4) {
                        const float4 hv = *reinterpret_cast<const float4*>(&hrow[j]);
                        const float4 wv = *reinterpret_cast<const float4*>(&wrow[j]);
                        a = fmaf(hv.x, wv.x, a); a = fmaf(hv.y, wv.y, a);
                        a = fmaf(hv.z, wv.z, a); a = fmaf(hv.w, wv.w, a);
                    }
                    head_acc[i] = a;
                }
            }
        }
        __syncthreads();
    }

#pragma unroll
    for (int i = 0; i < CPT; ++i) {
        const int c = hq * CPT + i;
        if (c < CT) s_logits[hr][c] = head_acc[i];
    }
    __syncthreads();

    if constexpr (MODE == 0) {
        if (tid < 64) {
            const int g = s_idx[tid];
            float m = s_logits[tid][0]; int am = 0;
#pragma unroll
            for (int j = 1; j < 8; ++j) { const float x = s_logits[tid][j]; if (x > m) { m = x; am = j; } }
            float s = 0.f;
#pragma unroll
            for (int j = 0; j < 8; ++j) s += expf(s_logits[tid][j] - m);
            out[3 * Bn + g] = (float)am;
            out[4 * Bn + g] = s_logits[tid][8];
            out[5 * Bn + g] = -logf(s);
        }
    } else if constexpr (MODE == 1) {
        if (tid < 64) {
            const int g = s_idx[tid];
            const int eo = execopt[g];
            const float p = 1.f / (1.f + expf(-s_logits[tid][eo]));
            out[6 * Bn + g] = p;
            bool dn;
            if (*dflag) dn = ((const unsigned char*)dones)[g] != 0;
            else        dn = ((const int*)dones)[g] != 0;
            const int no = (dn || (p > 0.5f)) ? (int)out[3 * Bn + g] : eo;
            const int pos = atomicAdd(&counts[no], 1);
            buckets[no * Bn + pos] = (unsigned short)g;
        }
    } else {
        if (tid < nrows) {
            const int g = s_idx[tid];
            float m = s_logits[tid][0]; int am = 0;
#pragma unroll
            for (int j = 1; j < 16; ++j) { const float x = s_logits[tid][j]; if (x > m) { m = x; am = j; } }
            float s = 0.f;
#pragma unroll
            for (int j = 0; j < 16; ++j) s += expf(s_logits[tid][j] - m);
            out[0 * Bn + g] = (float)am;
            out[1 * Bn + g] = s_logits[tid][16];
            out[2 * Bn + g] = -logf(s);
        }
    }
}

// ---------------- launcher ----------------
extern "C" void kernel_launch(void* const* d_in, const int* in_sizes, int n_in,
                              void* d_out, int out_size, void* d_ws, size_t ws_size,
                              hipStream_t stream)
{
    const float* obs     = (const float*)d_in[0];
    const void*  dones   = d_in[1];
    const int*   execopt = (const int*)d_in[2];
    const float* Wm1   = (const float*)d_in[3];
    const float* bm1   = (const float*)d_in[4];
    const float* Wm_pi = (const float*)d_in[5];
    const float* Wm_v  = (const float*)d_in[6];
    const float* Wt1   = (const float*)d_in[7];
    const float* Wt2   = (const float*)d_in[8];
    const float* W1    = (const float*)d_in[9];
    const float* b1    = (const float*)d_in[10];
    const float* Wpi   = (const float*)d_in[11];
    const float* Wv    = (const float*)d_in[12];
    float* out = (float*)d_out;

    unsigned char* ws = (unsigned char*)d_ws;
    int* counts = (int*)(ws + WS_COUNTS);
    int* dflag  = (int*)(ws + WS_DFLAG);
    unsigned short* buckets = (unsigned short*)(ws + WS_BUCKETS);

    hipMemsetAsync(d_ws, 0, 64, stream);
    k_detect<<<1, 256, 0, stream>>>((const unsigned int*)dones, dflag);

    if (ws_size >= MID_NEED) {
        float* metaL = (float*)(ws + WS_LOGITS);
        float* termL = (float*)(ws + WS_LOGITS + LOG_SZ);
        float* subL  = (float*)(ws + WS_LOGITS + 2 * LOG_SZ);
        unsigned short* hidPl  = (unsigned short*)(ws + WS_HID);
        unsigned short* headPl = (unsigned short*)(ws + WS_HEAD);
        unsigned short* obsPl  = (unsigned short*)(ws + WS_OBS);

        hipMemsetAsync(ws + WS_LOGITS, 0, 3 * LOG_SZ, stream);
        k_split_hid<<<1280, 256, 0, stream>>>(Wm1, Wt1, W1, hidPl);
        k_split_head<<<320, 256, 0, stream>>>(Wm_pi, Wm_v, Wt2, Wpi, Wv, headPl);

        if (ws_size >= FULL_NEED) {
            k_split_obs<<<8192, 256, 0, stream>>>(obs, obsPl);
            k_gemm<3, true><<<4096, 256, 0, stream>>>(
                obs, obsPl, hidPl, headPl, bm1, b1, metaL, termL, subL, counts, buckets);
            k_epi_mt<<<128, 256, 0, stream>>>(metaL, termL, out, execopt, dones, dflag, counts, buckets);
            k_gemm<2, true><<<16384, 256, 0, stream>>>(
                obs, obsPl, hidPl, headPl, bm1, b1, metaL, termL, subL, counts, buckets);
            k_epi_sub<<<128, 256, 0, stream>>>(subL, out);
        } else {
            k_gemm<3, false><<<4096, 256, 0, stream>>>(
                obs, nullptr, hidPl, headPl, bm1, b1, metaL, termL, subL, counts, buckets);
            k_epi_mt<<<128, 256, 0, stream>>>(metaL, termL, out, execopt, dones, dflag, counts, buckets);
            k_gemm<2, false><<<16384, 256, 0, stream>>>(
                obs, nullptr, hidPl, headPl, bm1, b1, metaL, termL, subL, counts, buckets);
            k_epi_sub<<<128, 256, 0, stream>>>(subL, out);
        }
    } else {
        k_fused_fb<8, 1, true, 0><<<Bn / 64, 256, 0, stream>>>(
            obs, Wm1, bm1, Wm_pi, Wm_v, out, counts, buckets, dones, dflag, execopt);
        k_fused_fb<8, 0, false, 1><<<Bn / 64, 256, 0, stream>>>(
            obs, Wt1, nullptr, Wt2, nullptr, out, counts, buckets, dones, dflag, execopt);
        k_fused_fb<16, 1, true, 2><<<8 * (Bn / 64), 256, 0, stream>>>(
            obs, W1, b1, Wpi, Wv, out, counts, buckets, dones, dflag, execopt);
    }
}